// Round 8
// baseline (136.811 us; speedup 1.0000x reference)
//
#include <hip/hip_runtime.h>
#include <hip/hip_bf16.h>

#define NB   32
#define NQ   300
#define NCLS 92
#define NM   50
#define BM   (NB * NM)   // 1600 flat targets
#define BQ   (NB * NQ)   // 9600 flat preds
#define HM   NQ          // hungarian cols (queries) = 300
#define HN   NM          // hungarian rows (targets) = 50
#define PITCH 305        // 305 % 32 = 17 (odd): row-scan & col-mode <=2-way (free)
#define BIG  1e30f
#define HUNG_BLOCKS NB
#define COST_ROWS_PER_BLOCK 16
#define COST_BLOCKS (BQ / COST_ROWS_PER_BLOCK)  // 600
#define NBLOCKS (HUNG_BLOCKS + COST_BLOCKS)     // 632

typedef float vf4 __attribute__((ext_vector_type(4)));

// single-wave fence: equivalent to __syncthreads() when one wave executes
#define FENCE() __threadfence_block()

__device__ __forceinline__ float wred_max(float v) {
#pragma unroll
  for (int m = 1; m < 64; m <<= 1) v = fmaxf(v, __shfl_xor(v, m, 64));
  return v;
}
__device__ __forceinline__ float wred_sum(float v) {
#pragma unroll
  for (int m = 1; m < 64; m <<= 1) v += __shfl_xor(v, m, 64);
  return v;
}
__device__ __forceinline__ float wred_min(float v) {
#pragma unroll
  for (int m = 1; m < 64; m <<= 1) v = fminf(v, __shfl_xor(v, m, 64));
  return v;
}

// reg-array select by wave-uniform index (stays in VGPRs)
__device__ __forceinline__ int sel5i(const int* a, int k) {
  int r = a[0];
#pragma unroll
  for (int t = 1; t < 5; t++) r = (k == t) ? a[t] : r;
  return r;
}

// cost(pred, target): -prob + 5*L1 - 2*GIoU  — R2-identical precise arithmetic
__device__ __forceinline__ float pair_cost(float ax1, float ay1, float ax2,
                                           float ay2, float areaA,
                                           const float4& pb, const float4& t,
                                           float negprob) {
  float cb = fabsf(pb.x - t.x) + fabsf(pb.y - t.y) +
             fabsf(pb.z - t.z) + fabsf(pb.w - t.w);
  float bx1 = t.x - 0.5f * t.z, by1 = t.y - 0.5f * t.w;
  float bx2 = t.x + 0.5f * t.z, by2 = t.y + 0.5f * t.w;
  float areaB = (bx2 - bx1) * (by2 - by1);
  float iw = fmaxf(fminf(ax2, bx2) - fmaxf(ax1, bx1), 0.f);
  float ih = fmaxf(fminf(ay2, by2) - fmaxf(ay1, by1), 0.f);
  float inter = iw * ih;
  float uni = areaA + areaB - inter;
  float iou = inter / uni;
  float ew = fmaxf(fmaxf(ax2, bx2) - fminf(ax1, bx1), 0.f);
  float eh = fmaxf(fmaxf(ay2, by2) - fminf(ay1, by1), 0.f);
  float areaE = ew * eh;
  float giou = iou - (areaE - uni) / areaE;
  return (negprob + 5.f * cb) - 2.f * giou;
}

// wave-cooperative softmax over 92 classes -> prow[0..91] (precise expf, div)
__device__ __forceinline__ void wave_softmax(const float* __restrict__ lrow,
                                             float* prow, int lane) {
  float x0 = (lane < NCLS) ? lrow[lane] : -BIG;
  float x1 = (lane + 64 < NCLS) ? lrow[lane + 64] : -BIG;
  float mx = wred_max(fmaxf(x0, x1));
  float e0 = expf(x0 - mx), e1 = expf(x1 - mx);
  float s = wred_sum(e0 + e1);
  if (lane < NCLS) prow[lane] = e0 / s;
  if (lane + 64 < NCLS) prow[lane + 64] = e1 / s;
  FENCE();
}

__global__ __launch_bounds__(1024) void fused_kernel(
    const float* __restrict__ logits, const float* __restrict__ pboxes,
    const int* __restrict__ tlab, const float* __restrict__ tbox,
    float* __restrict__ outp) {
  __shared__ float hc[HN * PITCH];      // 61000 B (hungarian path only)
  __shared__ float probs_s[16][NCLS];   // 5888 B (both paths)
  __shared__ int   qarr[HN];

  float* C = outp + 2 * BM;
  int tid = threadIdx.x, wave = tid >> 6, lane = tid & 63;

  if (blockIdx.x >= HUNG_BLOCKS) {
    // ---------------- cost-matrix path: one pred row per wave ----------------
    int row = (blockIdx.x - HUNG_BLOCKS) * COST_ROWS_PER_BLOCK + wave;
    wave_softmax(logits + (size_t)row * NCLS, probs_s[wave], lane);

    float4 pb = reinterpret_cast<const float4*>(pboxes)[row];
    float ax1 = pb.x - 0.5f * pb.z, ay1 = pb.y - 0.5f * pb.w;
    float ax2 = pb.x + 0.5f * pb.z, ay2 = pb.y + 0.5f * pb.w;
    float areaA = (ax2 - ax1) * (ay2 - ay1);

    const float4* tbv = reinterpret_cast<const float4*>(tbox);
    const int4*   tlv = reinterpret_cast<const int4*>(tlab);
    vf4* crow = reinterpret_cast<vf4*>(C + (size_t)row * BM);
    for (int q4 = lane; q4 < BM / 4; q4 += 64) {
      int4 cls = tlv[q4];
      int clsa[4] = {cls.x, cls.y, cls.z, cls.w};
      vf4 o;
#pragma unroll
      for (int e = 0; e < 4; e++) {
        float4 t = tbv[q4 * 4 + e];
        o[e] = pair_cost(ax1, ay1, ax2, ay2, areaA, pb, t,
                         -probs_s[wave][clsa[e]]);
      }
      __builtin_nontemporal_store(o, &crow[q4]);
    }
    return;
  }

  // ---------------- hungarian path: batch b = blockIdx.x ----------------
  int b = blockIdx.x;

  // preload this batch's 50 targets into lane registers
  float4 t_reg = make_float4(0.f, 0.f, 0.f, 0.f);
  int cls_reg = 0;
  if (lane < NM) {
    t_reg = reinterpret_cast<const float4*>(tbox)[b * NM + lane];
    cls_reg = tlab[b * NM + lane];
  }

  // stage hc[i][q] = cost(pred (b,q), target (b,i)) with all 16 waves
  const float4* pbv = reinterpret_cast<const float4*>(pboxes);
  for (int q = wave; q < NQ; q += 16) {
    wave_softmax(logits + (size_t)(b * NQ + q) * NCLS, probs_s[wave], lane);
    float4 pb = pbv[b * NQ + q];
    float ax1 = pb.x - 0.5f * pb.z, ay1 = pb.y - 0.5f * pb.w;
    float ax2 = pb.x + 0.5f * pb.z, ay2 = pb.y + 0.5f * pb.w;
    float areaA = (ax2 - ax1) * (ay2 - ay1);
    if (lane < NM) {
      float negp = -probs_s[wave][cls_reg];
      hc[lane * PITCH + q] =
          pair_cost(ax1, ay1, ax2, ay2, areaA, pb, t_reg, negp);
    }
  }
  __syncthreads();            // all 16 waves alive here
  if (wave != 0) return;      // wave 0 continues barrier-free (single wave)

  // ===== R6's ALGORITHM on register machinery (R5-verified-by-agreement) =====
  // v = 0 start; greedy: row i -> its row-argmin col if free. NO col-reduction
  // (falsified in R5/R7: identical wrong outputs; R6's init is the verified one).

  // ---- row reduction: lane i scans its row; u_reg = min, am_reg = argmin ----
  float u_reg = 0.f;
  int am_reg = 0;
  if (lane < HN) {
    float mn = BIG; int amv = 0;
    for (int j = 0; j < HM; j++) {
      float vv = hc[lane * PITCH + j];
      if (vv < mn) { mn = vv; amv = j; }
    }
    u_reg = mn; am_reg = amv;
  }

  // ---- greedy tight-edge assignment (R6 semantics, register p) ----
  int p_r[5];
#pragma unroll
  for (int k = 0; k < 5; k++) p_r[k] = -1;
  unsigned long long pending = 0;
  for (int i = 0; i < HN; i++) {
    int jm = __shfl(am_reg, i, 64);
    int kk = jm >> 6, ll = jm & 63;
    int cur = __shfl(sel5i(p_r, kk), ll, 64);
    if (cur == -1) {
#pragma unroll
      for (int k = 0; k < 5; k++)
        if (k == kk && lane == ll) p_r[k] = i;
    } else {
      pending |= 1ull << i;
    }
  }

  // ---- JV augmenting searches (R5 machinery; v starts at 0) ----
  float v_r[5], minv_r[5];
  int way_r[5];
#pragma unroll
  for (int k = 0; k < 5; k++) v_r[k] = 0.f;

  while (pending) {
    int i_start = (int)__ffsll((long long)pending) - 1;
    pending &= pending - 1;
#pragma unroll
    for (int k = 0; k < 5; k++) minv_r[k] = BIG;
    unsigned usedc = 0;
    unsigned long long used_rows = 1ull << i_start;
    int i0 = i_start, j0 = HM, jfree = -1;

    while (true) {
      float ui0 = __shfl(u_reg, i0, 64);
      float best = BIG; int bj = 0;
#pragma unroll
      for (int k = 0; k < 5; k++) {
        int j = lane + 64 * k;
        if (j < HM && !((usedc >> k) & 1u)) {
          float cur = hc[i0 * PITCH + j] - ui0 - v_r[k];
          if (cur < minv_r[k]) { minv_r[k] = cur; way_r[k] = j0; }
          if (minv_r[k] < best) { best = minv_r[k]; bj = j; }
        }
      }
      // R6-verbatim tie-break: min value, lowest lane among equals
      float wmin = wred_min(best);
      unsigned long long ball = __ballot(best == wmin);
      int src = (int)__ffsll((long long)ball) - 1;
      int j1 = __shfl(bj, src, 64);
      float delta = wmin;

      // dual updates (used set EXCLUDES j1, matching ref ordering);
      // virtual col HM: u[i_start] += delta via used_rows, no v/minv slot
      if ((used_rows >> lane) & 1ull) u_reg += delta;
#pragma unroll
      for (int k = 0; k < 5; k++) {
        int j = lane + 64 * k;
        if (j < HM) {
          if ((usedc >> k) & 1u) v_r[k] -= delta;
          else                   minv_r[k] -= delta;
        }
      }
      // mark j1 used; fetch p[j1]
      int k1 = j1 >> 6, l1 = j1 & 63;
      if (lane == l1) usedc |= 1u << k1;
      int psel = __shfl(sel5i(p_r, k1), l1, 64);
      if (psel == -1) { jfree = j1; break; }
      i0 = psel;
      used_rows |= 1ull << i0;
      j0 = j1;
    }

    // augment: walk way from jfree back to the virtual col
    int jj = jfree;
    while (true) {
      int kk = jj >> 6, ll = jj & 63;
      int wsel = __shfl(sel5i(way_r, kk), ll, 64);
      int pv;
      if (wsel == HM) {
        pv = i_start;
      } else {
        pv = __shfl(sel5i(p_r, wsel >> 6), wsel & 63, 64);
      }
#pragma unroll
      for (int k = 0; k < 5; k++)
        if (k == kk && lane == ll) p_r[k] = pv;
      if (wsel == HM) break;
      jj = wsel;
    }
  }

  // ---- emit: q[i] = col of row i; rank-sort; write as float32 ----
#pragma unroll
  for (int k = 0; k < 5; k++) {
    int j = lane + 64 * k;
    if (j < HM && p_r[k] >= 0) qarr[p_r[k]] = j;
  }
  FENCE();
  if (lane < HN) {
    int qi = qarr[lane];
    int rank = 0;
    for (int t = 0; t < HN; t++) rank += (qarr[t] < qi);
    outp[(size_t)b * NM + rank] = (float)qi;         // pred_idx
    outp[BM + (size_t)b * NM + rank] = (float)lane;  // gt_idx
  }
}

extern "C" void kernel_launch(void* const* d_in, const int* in_sizes, int n_in,
                              void* d_out, int out_size, void* d_ws, size_t ws_size,
                              hipStream_t stream) {
  const float* logits = (const float*)d_in[0];   // (32,300,92)
  const float* pboxes = (const float*)d_in[1];   // (32,300,4)
  const int*   tlab   = (const int*)d_in[2];     // (32,50)
  const float* tbox   = (const float*)d_in[3];   // (32,50,4)
  float* out = (float*)d_out;

  fused_kernel<<<dim3(NBLOCKS), dim3(1024), 0, stream>>>(
      logits, pboxes, tlab, tbox, out);
}

// Round 9
// 125.468 us; speedup vs baseline: 1.0904x; 1.0904x over previous
//
#include <hip/hip_runtime.h>
#include <hip/hip_bf16.h>

#define NB   32
#define NQ   300
#define NCLS 92
#define NM   50
#define BM   (NB * NM)   // 1600 flat targets
#define BQ   (NB * NQ)   // 9600 flat preds
#define HM   NQ          // hungarian cols (queries) = 300
#define HN   NM          // hungarian rows (targets) = 50
#define PITCH 305        // 305 % 32 = 17 (odd): row-scan & col-mode <=2-way (free)
#define BIG  1e30f
#define HUNG_BLOCKS NB
#define COST_ROWS_PER_BLOCK 16
#define COST_BLOCKS (BQ / COST_ROWS_PER_BLOCK)  // 600
#define NBLOCKS (HUNG_BLOCKS + COST_BLOCKS)     // 632

typedef float vf4 __attribute__((ext_vector_type(4)));

// single-wave fence: equivalent to __syncthreads() when one wave executes
#define FENCE() __threadfence_block()

__device__ __forceinline__ float wred_max(float v) {
#pragma unroll
  for (int m = 1; m < 64; m <<= 1) v = fmaxf(v, __shfl_xor(v, m, 64));
  return v;
}
__device__ __forceinline__ float wred_sum(float v) {
#pragma unroll
  for (int m = 1; m < 64; m <<= 1) v += __shfl_xor(v, m, 64);
  return v;
}
__device__ __forceinline__ float wred_min(float v) {
#pragma unroll
  for (int m = 1; m < 64; m <<= 1) v = fminf(v, __shfl_xor(v, m, 64));
  return v;
}

// cost(pred, target): -prob + 5*L1 - 2*GIoU  — R2-identical precise arithmetic
__device__ __forceinline__ float pair_cost(float ax1, float ay1, float ax2,
                                           float ay2, float areaA,
                                           const float4& pb, const float4& t,
                                           float negprob) {
  float cb = fabsf(pb.x - t.x) + fabsf(pb.y - t.y) +
             fabsf(pb.z - t.z) + fabsf(pb.w - t.w);
  float bx1 = t.x - 0.5f * t.z, by1 = t.y - 0.5f * t.w;
  float bx2 = t.x + 0.5f * t.z, by2 = t.y + 0.5f * t.w;
  float areaB = (bx2 - bx1) * (by2 - by1);
  float iw = fmaxf(fminf(ax2, bx2) - fmaxf(ax1, bx1), 0.f);
  float ih = fmaxf(fminf(ay2, by2) - fmaxf(ay1, by1), 0.f);
  float inter = iw * ih;
  float uni = areaA + areaB - inter;
  float iou = inter / uni;
  float ew = fmaxf(fmaxf(ax2, bx2) - fminf(ax1, bx1), 0.f);
  float eh = fmaxf(fmaxf(ay2, by2) - fminf(ay1, by1), 0.f);
  float areaE = ew * eh;
  float giou = iou - (areaE - uni) / areaE;
  return (negprob + 5.f * cb) - 2.f * giou;
}

// wave-cooperative softmax over 92 classes -> prow[0..91] (precise expf, div)
__device__ __forceinline__ void wave_softmax(const float* __restrict__ lrow,
                                             float* prow, int lane) {
  float x0 = (lane < NCLS) ? lrow[lane] : -BIG;
  float x1 = (lane + 64 < NCLS) ? lrow[lane + 64] : -BIG;
  float mx = wred_max(fmaxf(x0, x1));
  float e0 = expf(x0 - mx), e1 = expf(x1 - mx);
  float s = wred_sum(e0 + e1);
  if (lane < NCLS) prow[lane] = e0 / s;
  if (lane + 64 < NCLS) prow[lane + 64] = e1 / s;
  FENCE();
}

__global__ __launch_bounds__(1024) void fused_kernel(
    const float* __restrict__ logits, const float* __restrict__ pboxes,
    const int* __restrict__ tlab, const float* __restrict__ tbox,
    float* __restrict__ outp) {
  __shared__ float hc[HN * PITCH];      // 61000 B (hungarian path only)
  __shared__ float probs_s[16][NCLS];   // 5888 B (both paths)
  __shared__ int   p[HM + 1];
  __shared__ int   way[HM];
  __shared__ int   qarr[HN];

  float* C = outp + 2 * BM;
  int tid = threadIdx.x, wave = tid >> 6, lane = tid & 63;

  if (blockIdx.x >= HUNG_BLOCKS) {
    // ---------------- cost-matrix path: one pred row per wave ----------------
    int row = (blockIdx.x - HUNG_BLOCKS) * COST_ROWS_PER_BLOCK + wave;
    wave_softmax(logits + (size_t)row * NCLS, probs_s[wave], lane);

    float4 pb = reinterpret_cast<const float4*>(pboxes)[row];
    float ax1 = pb.x - 0.5f * pb.z, ay1 = pb.y - 0.5f * pb.w;
    float ax2 = pb.x + 0.5f * pb.z, ay2 = pb.y + 0.5f * pb.w;
    float areaA = (ax2 - ax1) * (ay2 - ay1);

    const float4* tbv = reinterpret_cast<const float4*>(tbox);
    const int4*   tlv = reinterpret_cast<const int4*>(tlab);
    vf4* crow = reinterpret_cast<vf4*>(C + (size_t)row * BM);
    for (int q4 = lane; q4 < BM / 4; q4 += 64) {
      int4 cls = tlv[q4];
      int clsa[4] = {cls.x, cls.y, cls.z, cls.w};
      vf4 o;
#pragma unroll
      for (int e = 0; e < 4; e++) {
        float4 t = tbv[q4 * 4 + e];
        o[e] = pair_cost(ax1, ay1, ax2, ay2, areaA, pb, t,
                         -probs_s[wave][clsa[e]]);
      }
      __builtin_nontemporal_store(o, &crow[q4]);
    }
    return;
  }

  // ---------------- hungarian path: batch b = blockIdx.x ----------------
  int b = blockIdx.x;

  // init p (all threads; covered by the barrier below)
  for (int x = tid; x <= HM; x += 1024) p[x] = -1;

  // preload this batch's 50 targets into lane registers
  float4 t_reg = make_float4(0.f, 0.f, 0.f, 0.f);
  int cls_reg = 0;
  if (lane < NM) {
    t_reg = reinterpret_cast<const float4*>(tbox)[b * NM + lane];
    cls_reg = tlab[b * NM + lane];
  }

  // stage hc[i][q] = cost(pred (b,q), target (b,i)) with all 16 waves
  const float4* pbv = reinterpret_cast<const float4*>(pboxes);
  for (int q = wave; q < NQ; q += 16) {
    wave_softmax(logits + (size_t)(b * NQ + q) * NCLS, probs_s[wave], lane);
    float4 pb = pbv[b * NQ + q];
    float ax1 = pb.x - 0.5f * pb.z, ay1 = pb.y - 0.5f * pb.w;
    float ax2 = pb.x + 0.5f * pb.z, ay2 = pb.y + 0.5f * pb.w;
    float areaA = (ax2 - ax1) * (ay2 - ay1);
    if (lane < NM) {
      float negp = -probs_s[wave][cls_reg];
      hc[lane * PITCH + q] =
          pair_cost(ax1, ay1, ax2, ay2, areaA, pb, t_reg, negp);
    }
  }
  __syncthreads();            // all 16 waves alive here
  if (wave != 0) return;      // wave 0 continues barrier-free (single wave)

  // ===== R6 ALGORITHM (v=0, row-argmin greedy, R6 tie-break) with u in =====
  // ===== registers, p/way in LDS, prefetched p[j1], no per-round FENCE =====

  // ---- row reduction: lane i scans its row; u_reg = min, am_reg = argmin ----
  float u_reg = 0.f;
  int am_reg = 0;
  if (lane < HN) {
    float mn = BIG; int amv = 0;
    for (int j = 0; j < HM; j++) {
      float vv = hc[lane * PITCH + j];
      if (vv < mn) { mn = vv; amv = j; }
    }
    u_reg = mn; am_reg = amv;
  }

  // ---- greedy tight-edge assignment (R6 semantics; register assigned-mask) --
  unsigned amask = 0;   // bit k of lane l: col l+64k assigned
  unsigned long long pending = 0;
  for (int i = 0; i < HN; i++) {
    int jm = __shfl(am_reg, i, 64);
    unsigned mrem = __shfl(amask, jm & 63, 64);
    if (!((mrem >> (jm >> 6)) & 1u)) {
      if (lane == (jm & 63)) amask |= 1u << (jm >> 6);
      if (lane == 0) p[jm] = i;
    } else {
      pending |= 1ull << i;
    }
  }
  FENCE();

  // ---- JV augmenting searches ----
  float v_r[5], minv_r[5];
#pragma unroll
  for (int k = 0; k < 5; k++) v_r[k] = 0.f;

  while (pending) {
    int i_start = (int)__ffsll((long long)pending) - 1;
    pending &= pending - 1;
#pragma unroll
    for (int k = 0; k < 5; k++) minv_r[k] = BIG;
    unsigned usedc = 0;
    unsigned long long used_rows = 1ull << i_start;
    int i0 = i_start, j0 = HM, jfree = -1;
    float ui0 = __shfl(u_reg, i0, 64);

    while (true) {
      float best = BIG; int bj = 0;
#pragma unroll
      for (int k = 0; k < 5; k++) {
        int j = lane + 64 * k;
        if (j < HM && !((usedc >> k) & 1u)) {
          float cur = hc[i0 * PITCH + j] - ui0 - v_r[k];
          if (cur < minv_r[k]) { minv_r[k] = cur; way[j] = j0; }
          if (minv_r[k] < best) { best = minv_r[k]; bj = j; }
        }
      }
      // R6-verbatim tie-break: min value, lowest lane among equals
      float wmin = wred_min(best);
      unsigned long long ball = __ballot(best == wmin);
      int src = (int)__ffsll((long long)ball) - 1;
      int j1 = __shfl(bj, src, 64);
      float delta = wmin;

      int psel = p[j1];   // LDS read issued early; overlaps dual update below

      // dual updates (used set EXCLUDES j1, matching ref ordering);
      // virtual col: u[i_start] += delta via used_rows bit
      if ((used_rows >> lane) & 1ull) u_reg += delta;
#pragma unroll
      for (int k = 0; k < 5; k++) {
        int j = lane + 64 * k;
        if (j < HM) {
          if ((usedc >> k) & 1u) v_r[k] -= delta;
          else                   minv_r[k] -= delta;
        }
      }
      if (lane == (j1 & 63)) usedc |= 1u << (j1 >> 6);

      if (psel == -1) { jfree = j1; break; }
      i0 = psel;
      used_rows |= 1ull << i0;
      ui0 = __shfl(u_reg, i0, 64);  // new row not in used set: value is final
      j0 = j1;
    }

    // augment along `way` (all lanes identical walk; same-value writes)
    int jj = jfree;
    while (jj != HM) {
      int jn = way[jj];
      int pv = (jn == HM) ? i_start : p[jn];
      p[jj] = pv;
      jj = jn;
    }
    FENCE();
  }

  // ---- emit: q[i] = col of row i; rank-sort; write as float32 ----
  for (int j = lane; j < HM; j += 64) {
    int r = p[j];
    if (r >= 0) qarr[r] = j;
  }
  FENCE();
  if (lane < HN) {
    int qi = qarr[lane];
    int rank = 0;
    for (int t = 0; t < HN; t++) rank += (qarr[t] < qi);
    outp[(size_t)b * NM + rank] = (float)qi;         // pred_idx
    outp[BM + (size_t)b * NM + rank] = (float)lane;  // gt_idx
  }
}

extern "C" void kernel_launch(void* const* d_in, const int* in_sizes, int n_in,
                              void* d_out, int out_size, void* d_ws, size_t ws_size,
                              hipStream_t stream) {
  const float* logits = (const float*)d_in[0];   // (32,300,92)
  const float* pboxes = (const float*)d_in[1];   // (32,300,4)
  const int*   tlab   = (const int*)d_in[2];     // (32,50)
  const float* tbox   = (const float*)d_in[3];   // (32,50,4)
  float* out = (float*)d_out;

  fused_kernel<<<dim3(NBLOCKS), dim3(1024), 0, stream>>>(
      logits, pboxes, tlab, tbox, out);
}